// Round 9
// baseline (4137.062 us; speedup 1.0000x reference)
//
#include <hip/hip_runtime.h>
#include <hip/hip_bf16.h>

#define VOCAB  32000
#define HIDDEN 256
#define NHASH  20
#define MROWS  4096           // 2 * 2048
#define KDIM   256
#define POOL   100000
#define NTILES (VOCAB / 128)  // 250

typedef __attribute__((ext_vector_type(8))) short bf16x8;
typedef __attribute__((ext_vector_type(4))) float f32x4;

__device__ __forceinline__ unsigned short f32_bf16_rne(float f) {
  union { float f; unsigned int u; } v; v.f = f;
  unsigned int r = v.u + 0x7FFF + ((v.u >> 16) & 1);   // round-to-nearest-even
  return (unsigned short)(r >> 16);
}

__device__ __forceinline__ float bf16_f32(unsigned short u) {
  union { unsigned int u; float f; } v; v.u = (unsigned int)u << 16;
  return v.f;
}

__device__ __forceinline__ void async16(const void* g, void* l) {
  __builtin_amdgcn_global_load_lds(
      (const __attribute__((address_space(1))) unsigned int*)g,
      (__attribute__((address_space(3))) unsigned int*)l, 16, 0, 0);
}

__device__ __forceinline__ ushort4 f4_to_bf4(float4 f) {
  ushort4 o;
  o.x = f32_bf16_rne(f.x); o.y = f32_bf16_rne(f.y);
  o.z = f32_bf16_rne(f.z); o.w = f32_bf16_rne(f.w);
  return o;
}

// Streamed cast of pool + x to bf16. Grid-stride over float4s.
#define POOL_F4 (POOL * HIDDEN / 4)          // 6,400,000
#define X_F4    (MROWS * HIDDEN / 4)         // 262,144
__global__ __launch_bounds__(256)
void cast_kernel(const float* __restrict__ x, const float* __restrict__ pool,
                 unsigned short* __restrict__ xb, unsigned short* __restrict__ poolb) {
  const int step = gridDim.x * 256;
  for (int i = blockIdx.x * 256 + threadIdx.x; i < POOL_F4 + X_F4; i += step) {
    if (i < POOL_F4) {
      ((ushort4*)poolb)[i] = f4_to_bf4(((const float4*)pool)[i]);
    } else {
      const int j = i - POOL_F4;
      ((ushort4*)xb)[j] = f4_to_bf4(((const float4*)x)[j]);
    }
  }
}

// x-only cast (fallback when ws can't hold poolb)
__global__ __launch_bounds__(256)
void xcast_kernel(const float* __restrict__ x, unsigned short* __restrict__ xb) {
  const int i = blockIdx.x * 256 + threadIdx.x;   // X_F4 / 256 blocks
  ((ushort4*)xb)[i] = f4_to_bf4(((const float4*)x)[i]);
}

// GEMM with on-demand embed build (producer-consumer via per-ntile flags).
// Grid = 8000 blocks = 32 mtiles x 250 ntiles (R7 structure, 32 KB LDS,
// 5 blocks/CU). First block to reach an ntile builds its 128 eb rows
// (atomicCAS claim -> build -> release flag=2); others acquire-spin.
// Gathers overlap other blocks' MFMA + store drain instead of running as
// a separate serial kernel.
template <bool BF16POOL>
__global__ __launch_bounds__(256)
void gemm_kernel(const unsigned short* __restrict__ xb,
                 const unsigned short* __restrict__ poolb,
                 const float* __restrict__ poolf,
                 const float* __restrict__ w, const int* __restrict__ hash,
                 unsigned short* __restrict__ eb,
                 int* __restrict__ flags,
                 float* __restrict__ out) {
  __shared__ char smem[32768] __attribute__((aligned(128)));
  short* As = (short*)smem;
  short* Bs = (short*)(smem + 16384);
  float* Cs = (float*)smem;

  const int tid  = threadIdx.x;
  const int lane = tid & 63;
  const int wave = tid >> 6;
  const int wm   = wave >> 1;
  const int wn   = wave & 1;

  // bijective XCD swizzle: 8000 blocks, 8000 % 8 == 0
  const int bid  = blockIdx.x;
  const int swz  = (bid & 7) * 1000 + (bid >> 3);
  const int mtile = swz & 31;        // 32 M-tiles (consecutive blocks share ntile)
  const int ntile = swz >> 5;        // 250 N-tiles
  const int mbase = mtile * 128;
  const int nbase = ntile * 128;

  // ---- producer-consumer: ensure eb rows [nbase, nbase+128) are built ----
  {
    int* role = (int*)smem;          // smem unused until GEMM staging
    if (tid == 0) *role = atomicCAS(&flags[ntile], 0, 1);
    __syncthreads();
    const int st = *role;
    __syncthreads();                 // role read done before smem reuse

    if (st == 0) {
      // we build: wave w owns rows w*32 .. w*32+31
#pragma unroll 1
      for (int r = 0; r < 32; ++r) {
        const int row = wave * 32 + r;
        const int v   = nbase + row;
        int hl = 0; float wl = 0.f;
        if (lane < NHASH) {
          hl = hash[v * NHASH + lane];
          wl = w[v * NHASH + lane];
        }
        float4 a4 = make_float4(0.f, 0.f, 0.f, 0.f);
#pragma unroll
        for (int j = 0; j < NHASH; ++j) {
          const int   h  = __shfl(hl, j);
          const float ww = __shfl(wl, j);
          if (BF16POOL) {
            const ushort4 p = ((const ushort4*)(poolb + (size_t)h * HIDDEN))[lane];
            a4.x += ww * bf16_f32(p.x); a4.y += ww * bf16_f32(p.y);
            a4.z += ww * bf16_f32(p.z); a4.w += ww * bf16_f32(p.w);
          } else {
            const float4 p = ((const float4*)(poolf + (size_t)h * HIDDEN))[lane];
            a4.x += ww * p.x; a4.y += ww * p.y;
            a4.z += ww * p.z; a4.w += ww * p.w;
          }
        }
        ((ushort4*)(eb + (size_t)v * HIDDEN))[lane] = f4_to_bf4(a4);
      }
      __threadfence();               // each thread's eb stores device-visible
      __syncthreads();               // ... before the release below
      if (tid == 0)
        __hip_atomic_store(&flags[ntile], 2, __ATOMIC_RELEASE,
                           __HIP_MEMORY_SCOPE_AGENT);
    } else {
      if (tid == 0) {
        while (__hip_atomic_load(&flags[ntile], __ATOMIC_ACQUIRE,
                                 __HIP_MEMORY_SCOPE_AGENT) != 2)
          __builtin_amdgcn_s_sleep(8);
      }
      __syncthreads();
    }
  }

  // ---- GEMM (identical to R7) ----
  // staging: chunk c in [0,1024): row=c>>3, lds slot=c&7,
  // global colchunk = (c&7) ^ (row&7)   (pre-swizzled source, linear LDS dest)
  int srow[4], scol[4];
#pragma unroll
  for (int i = 0; i < 4; ++i) {
    const int c = i * 256 + tid;
    srow[i] = c >> 3;
    scol[i] = (((c & 7) ^ ((c >> 3) & 7)) << 3);
  }

  f32x4 acc[4][4] = {};

  const int abase = (wm * 64 + (lane & 15)) * 128;
  const int bbase = (wn * 64 + (lane & 15)) * 128;
  const int sw    = (lane & 7) << 4;
  const int kq    = (lane >> 4) << 4;     // 16B k-slot within 64B k-half

#pragma unroll
  for (int kt = 0; kt < 4; ++kt) {
    const int k0 = kt * 64;
#pragma unroll
    for (int i = 0; i < 4; ++i) {
      const int c = i * 256 + tid;
      async16(xb + (size_t)(mbase + srow[i]) * KDIM + k0 + scol[i], &As[c * 8]);
      async16(eb + (size_t)(nbase + srow[i]) * KDIM + k0 + scol[i], &Bs[c * 8]);
    }
    __syncthreads();   // compiler drains vmcnt(0) before barrier -> LDS visible

    const char* A = (const char*)As;
    const char* B = (const char*)Bs;
#pragma unroll
    for (int kk = 0; kk < 2; ++kk) {
      const int koff = (kk * 64 + kq) ^ sw;
      bf16x8 a[4], b[4];
#pragma unroll
      for (int mi = 0; mi < 4; ++mi)
        a[mi] = *(const bf16x8*)(A + abase + mi * 2048 + koff);
#pragma unroll
      for (int ni = 0; ni < 4; ++ni)
        b[ni] = *(const bf16x8*)(B + bbase + ni * 2048 + koff);
#pragma unroll
      for (int mi = 0; mi < 4; ++mi)
#pragma unroll
        for (int ni = 0; ni < 4; ++ni)
          acc[mi][ni] = __builtin_amdgcn_mfma_f32_16x16x32_bf16(
              a[mi], b[ni], acc[mi][ni], 0, 0, 0);
    }
    __syncthreads();   // readers done before next kt overwrites the buffer
  }

  // Epilogue: two 64-row phases through Cs[64][128], coalesced nt f32x4 rows.
  // C/D frag layout: col = lane&15, row = (lane>>4)*4 + reg (m89-verified).
#pragma unroll
  for (int ph = 0; ph < 2; ++ph) {
    if (wm == ph) {
      const int crow0 = (lane >> 4) << 2;             // 0..12 within 64-row half
      const int ccol  = wn * 64 + (lane & 15);
#pragma unroll
      for (int mi = 0; mi < 4; ++mi)
#pragma unroll
        for (int ni = 0; ni < 4; ++ni)
#pragma unroll
          for (int j = 0; j < 4; ++j)
            Cs[(crow0 + mi * 16 + j) * 128 + ccol + ni * 16] = acc[mi][ni][j];
    }
    __syncthreads();
#pragma unroll
    for (int i = 0; i < 8; ++i) {
      const int flat = i * 1024 + tid * 4;   // float index in 64x128 half-tile
      const int row  = flat >> 7;
      const int col  = flat & 127;
      f32x4 vv = *(const f32x4*)&Cs[row * 128 + col];
      __builtin_nontemporal_store(vv,
          (f32x4*)&out[(size_t)(mbase + ph * 64 + row) * VOCAB + nbase + col]);
    }
    if (ph == 0) __syncthreads();   // phase-0 reads done before wm==1 writes
  }
}

extern "C" void kernel_launch(void* const* d_in, const int* in_sizes, int n_in,
                              void* d_out, int out_size, void* d_ws, size_t ws_size,
                              hipStream_t stream) {
  const float* x    = (const float*)d_in[0];   // [2,2048,256]
  const float* pool = (const float*)d_in[1];   // [100000,256]
  const float* imp  = (const float*)d_in[2];   // [32000,20]
  const int*   hash = (const int*)d_in[3];     // [32000,20]
  float* out = (float*)d_out;                  // [2,2048,32000]

  unsigned short* xb    = (unsigned short*)d_ws;            // 2 MB bf16 x
  unsigned short* poolb = xb + (size_t)MROWS * HIDDEN;      // 51.2 MB bf16 pool
  unsigned short* eb    = poolb + (size_t)POOL * HIDDEN;    // 16.4 MB bf16 embed
  int*            flags = (int*)(eb + (size_t)VOCAB * HIDDEN);  // 250 ints

  const size_t need_full  = ((size_t)MROWS + POOL + VOCAB) * HIDDEN * 2 + 1024;
  const size_t need_small = ((size_t)MROWS + VOCAB) * HIDDEN * 2 + 1024;

  if (ws_size >= need_full) {
    hipMemsetAsync(flags, 0, 1024, stream);
    cast_kernel<<<2048, 256, 0, stream>>>(x, pool, xb, poolb);
    gemm_kernel<true><<<(MROWS / 128) * NTILES, 256, 0, stream>>>(
        xb, poolb, nullptr, imp, hash, eb, flags, out);
  } else {
    // small-ws fallback: eb right after xb, fp32 gathers
    unsigned short* eb2    = xb + (size_t)MROWS * HIDDEN;
    int*            flags2 = (int*)(eb2 + (size_t)VOCAB * HIDDEN);
    (void)need_small;
    hipMemsetAsync(flags2, 0, 1024, stream);
    xcast_kernel<<<X_F4 / 256, 256, 0, stream>>>(x, xb);
    gemm_kernel<false><<<(MROWS / 128) * NTILES, 256, 0, stream>>>(
        xb, nullptr, pool, imp, hash, eb2, flags2, out);
  }
}

// Round 10
// 189.463 us; speedup vs baseline: 21.8357x; 21.8357x over previous
//
#include <hip/hip_runtime.h>
#include <hip/hip_bf16.h>

#define VOCAB  32000
#define HIDDEN 256
#define NHASH  20
#define MROWS  4096           // 2 * 2048
#define KDIM   256
#define POOL   100000
#define XBLK   1024           // fallback cast blocks

typedef __attribute__((ext_vector_type(8))) short bf16x8;
typedef __attribute__((ext_vector_type(8))) unsigned short u16x8;
typedef __attribute__((ext_vector_type(4))) float f32x4;

__device__ __forceinline__ unsigned short f32_bf16_rne(float f) {
  union { float f; unsigned int u; } v; v.f = f;
  unsigned int r = v.u + 0x7FFF + ((v.u >> 16) & 1);   // round-to-nearest-even
  return (unsigned short)(r >> 16);
}

__device__ __forceinline__ float bf16_f32(unsigned short u) {
  union { unsigned int u; float f; } v; v.u = (unsigned int)u << 16;
  return v.f;
}

__device__ __forceinline__ void async16(const void* g, void* l) {
  __builtin_amdgcn_global_load_lds(
      (const __attribute__((address_space(1))) unsigned int*)g,
      (__attribute__((address_space(3))) unsigned int*)l, 16, 0, 0);
}

__device__ __forceinline__ ushort4 f4_to_bf4(float4 f) {
  ushort4 o;
  o.x = f32_bf16_rne(f.x); o.y = f32_bf16_rne(f.y);
  o.z = f32_bf16_rne(f.z); o.w = f32_bf16_rne(f.w);
  return o;
}

// Streamed cast of pool + x to bf16. Grid-stride over float4s.
#define POOL_F4 (POOL * HIDDEN / 4)          // 6,400,000
#define X_F4    (MROWS * HIDDEN / 4)         // 262,144
__global__ __launch_bounds__(256)
void cast_kernel(const float* __restrict__ x, const float* __restrict__ pool,
                 unsigned short* __restrict__ xb, unsigned short* __restrict__ poolb) {
  const int step = gridDim.x * 256;
  for (int i = blockIdx.x * 256 + threadIdx.x; i < POOL_F4 + X_F4; i += step) {
    if (i < POOL_F4) {
      ((ushort4*)poolb)[i] = f4_to_bf4(((const float4*)pool)[i]);
    } else {
      const int j = i - POOL_F4;
      ((ushort4*)xb)[j] = f4_to_bf4(((const float4*)x)[j]);
    }
  }
}

// One wave per vocab row, TWO hashes in flight at 16B/lane:
// lanes 0..31 gather hash j, lanes 32..63 gather hash j+1 (same columns),
// per-lane 8-col fp32 accumulate, shfl_xor(32) combine, half-wave store.
__global__ __launch_bounds__(256)
void embed_kernel(const unsigned short* __restrict__ poolb,
                  const float* __restrict__ w, const int* __restrict__ hash,
                  unsigned short* __restrict__ eb) {
  const int v    = blockIdx.x * 4 + (threadIdx.x >> 6);
  const int lane = threadIdx.x & 63;
  const int half = lane >> 5;          // which hash of the pair
  const int sub  = lane & 31;          // 16B chunk within the 512B row
  int   hl = 0; float wl = 0.f;
  if (lane < NHASH) {
    hl = hash[v * NHASH + lane];
    wl = w[v * NHASH + lane];
  }
  float acc[8] = {};
#pragma unroll
  for (int j = 0; j < NHASH; j += 2) {
    const int   h  = __shfl(hl, j + half);
    const float ww = __shfl(wl, j + half);
    const u16x8 p = *(const u16x8*)(poolb + (size_t)h * HIDDEN + sub * 8);
#pragma unroll
    for (int k = 0; k < 8; ++k) acc[k] += ww * bf16_f32(p[k]);
  }
#pragma unroll
  for (int k = 0; k < 8; ++k) acc[k] += __shfl_xor(acc[k], 32);
  if (lane < 32) {
    u16x8 o;
#pragma unroll
    for (int k = 0; k < 8; ++k) o[k] = f32_bf16_rne(acc[k]);
    *(u16x8*)(eb + (size_t)v * HIDDEN + sub * 8) = o;
  }
}

// Fallback (small ws): fused x-cast + fp32-gather embed.
__global__ __launch_bounds__(256)
void prep_kernel(const float* __restrict__ x, const float* __restrict__ pool,
                 const float* __restrict__ w, const int* __restrict__ hash,
                 unsigned short* __restrict__ xb, unsigned short* __restrict__ eb) {
  const int tid = threadIdx.x;
  if (blockIdx.x < XBLK) {
    const int i = blockIdx.x * 256 + tid;
    ((ushort4*)xb)[i] = f4_to_bf4(((const float4*)x)[i]);
    return;
  }
  const int v    = (blockIdx.x - XBLK) * 4 + (tid >> 6);
  const int lane = tid & 63;
  int   hl = 0; float wl = 0.f;
  if (lane < NHASH) {
    hl = hash[v * NHASH + lane];
    wl = w[v * NHASH + lane];
  }
  float4 acc = make_float4(0.f, 0.f, 0.f, 0.f);
#pragma unroll
  for (int j = 0; j < NHASH; ++j) {
    const int   h  = __shfl(hl, j);
    const float ww = __shfl(wl, j);
    const float4 p = ((const float4*)(pool + (size_t)h * HIDDEN))[lane];
    acc.x += ww * p.x; acc.y += ww * p.y;
    acc.z += ww * p.z; acc.w += ww * p.w;
  }
  ((ushort4*)(eb + (size_t)v * HIDDEN))[lane] = f4_to_bf4(acc);
}

// C[4096][32000] = Xb[4096][256] * Eb[32000][256]^T   (both operands [row][k])
// 128x128 tile, BK=64, 4 waves in 2x2, each wave 64x64 (4x4 frags of 16x16x32)
// Single-buffered 32 KB LDS -> 5 blocks/CU for cross-block overlap of
// prologue loads / epilogue store drain.  (R7 structure, proven 190 us.)
__global__ __launch_bounds__(256)
void gemm_kernel(const unsigned short* __restrict__ xb,
                 const unsigned short* __restrict__ eb,
                 float* __restrict__ out) {
  __shared__ char smem[32768] __attribute__((aligned(128)));
  short* As = (short*)smem;
  short* Bs = (short*)(smem + 16384);
  float* Cs = (float*)smem;

  const int tid  = threadIdx.x;
  const int lane = tid & 63;
  const int wave = tid >> 6;
  const int wm   = wave >> 1;
  const int wn   = wave & 1;

  // bijective XCD swizzle: 8000 blocks, 8000 % 8 == 0
  const int bid  = blockIdx.x;
  const int swz  = (bid & 7) * 1000 + (bid >> 3);
  const int mtile = swz & 31;        // 32 M-tiles (consecutive blocks share ntile)
  const int ntile = swz >> 5;        // 250 N-tiles
  const int mbase = mtile * 128;
  const int nbase = ntile * 128;

  // staging: chunk c in [0,1024): row=c>>3, lds slot=c&7,
  // global colchunk = (c&7) ^ (row&7)   (pre-swizzled source, linear LDS dest)
  int srow[4], scol[4];
#pragma unroll
  for (int i = 0; i < 4; ++i) {
    const int c = i * 256 + tid;
    srow[i] = c >> 3;
    scol[i] = (((c & 7) ^ ((c >> 3) & 7)) << 3);
  }

  f32x4 acc[4][4] = {};

  const int abase = (wm * 64 + (lane & 15)) * 128;
  const int bbase = (wn * 64 + (lane & 15)) * 128;
  const int sw    = (lane & 7) << 4;
  const int kq    = (lane >> 4) << 4;     // 16B k-slot within 64B k-half

#pragma unroll
  for (int kt = 0; kt < 4; ++kt) {
    const int k0 = kt * 64;
#pragma unroll
    for (int i = 0; i < 4; ++i) {
      const int c = i * 256 + tid;
      async16(xb + (size_t)(mbase + srow[i]) * KDIM + k0 + scol[i], &As[c * 8]);
      async16(eb + (size_t)(nbase + srow[i]) * KDIM + k0 + scol[i], &Bs[c * 8]);
    }
    __syncthreads();   // compiler drains vmcnt(0) before barrier -> LDS visible

    const char* A = (const char*)As;
    const char* B = (const char*)Bs;
#pragma unroll
    for (int kk = 0; kk < 2; ++kk) {
      const int koff = (kk * 64 + kq) ^ sw;
      bf16x8 a[4], b[4];
#pragma unroll
      for (int mi = 0; mi < 4; ++mi)
        a[mi] = *(const bf16x8*)(A + abase + mi * 2048 + koff);
#pragma unroll
      for (int ni = 0; ni < 4; ++ni)
        b[ni] = *(const bf16x8*)(B + bbase + ni * 2048 + koff);
#pragma unroll
      for (int mi = 0; mi < 4; ++mi)
#pragma unroll
        for (int ni = 0; ni < 4; ++ni)
          acc[mi][ni] = __builtin_amdgcn_mfma_f32_16x16x32_bf16(
              a[mi], b[ni], acc[mi][ni], 0, 0, 0);
    }
    __syncthreads();   // readers done before next kt overwrites the buffer
  }

  // Epilogue: two 64-row phases through Cs[64][128], coalesced nt f32x4 rows.
  // C/D frag layout: col = lane&15, row = (lane>>4)*4 + reg (m89-verified).
#pragma unroll
  for (int ph = 0; ph < 2; ++ph) {
    if (wm == ph) {
      const int crow0 = (lane >> 4) << 2;             // 0..12 within 64-row half
      const int ccol  = wn * 64 + (lane & 15);
#pragma unroll
      for (int mi = 0; mi < 4; ++mi)
#pragma unroll
        for (int ni = 0; ni < 4; ++ni)
#pragma unroll
          for (int j = 0; j < 4; ++j)
            Cs[(crow0 + mi * 16 + j) * 128 + ccol + ni * 16] = acc[mi][ni][j];
    }
    __syncthreads();
#pragma unroll
    for (int i = 0; i < 8; ++i) {
      const int flat = i * 1024 + tid * 4;   // float index in 64x128 half-tile
      const int row  = flat >> 7;
      const int col  = flat & 127;
      f32x4 vv = *(const f32x4*)&Cs[row * 128 + col];
      __builtin_nontemporal_store(vv,
          (f32x4*)&out[(size_t)(mbase + ph * 64 + row) * VOCAB + nbase + col]);
    }
    if (ph == 0) __syncthreads();   // phase-0 reads done before wm==1 writes
  }
}

extern "C" void kernel_launch(void* const* d_in, const int* in_sizes, int n_in,
                              void* d_out, int out_size, void* d_ws, size_t ws_size,
                              hipStream_t stream) {
  const float* x    = (const float*)d_in[0];   // [2,2048,256]
  const float* pool = (const float*)d_in[1];   // [100000,256]
  const float* imp  = (const float*)d_in[2];   // [32000,20]
  const int*   hash = (const int*)d_in[3];     // [32000,20]
  float* out = (float*)d_out;                  // [2,2048,32000]

  unsigned short* xb    = (unsigned short*)d_ws;                 // 2 MB bf16 x
  unsigned short* eb    = xb + (size_t)MROWS * HIDDEN;           // 16.4 MB bf16 embed
  unsigned short* poolb = eb + (size_t)VOCAB * HIDDEN;           // 51.2 MB bf16 pool

  const size_t need = ((size_t)MROWS + VOCAB + POOL) * HIDDEN * 2;
  if (ws_size >= need) {
    cast_kernel<<<2048, 256, 0, stream>>>(x, pool, xb, poolb);
    embed_kernel<<<VOCAB / 4, 256, 0, stream>>>(poolb, imp, hash, eb);
  } else {
    prep_kernel<<<XBLK + VOCAB / 4, 256, 0, stream>>>(x, pool, imp, hash, xb, eb);
  }
  gemm_kernel<<<(MROWS / 128) * (VOCAB / 128), 256, 0, stream>>>(xb, eb, out);
}